// Round 1
// baseline (1396.702 us; speedup 1.0000x reference)
//
#include <hip/hip_runtime.h>

// KmeansQuantizer: nearest-centroid assignment.
// feat [65536][768] f32, clusters [1024][768] f32 -> out [65536] int32
// argmin_c ||x-c||^2 == argmin_c (||c||^2 - 2 x.c)  (||x||^2 row-constant)

#define D_DIM 768
#define BM 128
#define BN 128
#define BK 32

// --- c2 kernel: one wave per cluster, ||c||^2 -> ws ---
__global__ __launch_bounds__(256) void c2_kernel(const float* __restrict__ clusters,
                                                 float* __restrict__ c2) {
    const int wave = threadIdx.x >> 6;
    const int lane = threadIdx.x & 63;
    const int c = blockIdx.x * 4 + wave;
    const float4* row = (const float4*)(clusters + (size_t)c * D_DIM);
    float s = 0.0f;
    #pragma unroll
    for (int k4 = 0; k4 < D_DIM / 4 / 64; ++k4) {       // 768/4 = 192 float4s, 3 per lane
        float4 v = row[k4 * 64 + lane];
        s += v.x * v.x + v.y * v.y + v.z * v.z + v.w * v.w;
    }
    #pragma unroll
    for (int off = 32; off > 0; off >>= 1) s += __shfl_down(s, off, 64);
    if (lane == 0) c2[c] = s;
}

// --- main kernel: 128x128 tile per block, fp32 VALU GEMM + running argmin ---
__global__ __launch_bounds__(256, 2) void argmin_kernel(const float* __restrict__ feat,
                                                        const float* __restrict__ clusters,
                                                        const float* __restrict__ c2,
                                                        int* __restrict__ out) {
    __shared__ float As[BK][BM];   // transposed: As[k][row], XOR-swizzled rows
    __shared__ float Bs[BK][BN];   // transposed: Bs[k][col], XOR-swizzled cols

    const int t  = threadIdx.x;
    const int tx = t & 15;         // col group
    const int ty = t >> 4;         // row group
    const int row0 = blockIdx.x * BM;

    // staging decomposition: per iter i, thread t loads float4 at
    // row r = i*32 + (t>>3), k-chunk kc = (t&7)*4.  Swizzle XOR for
    // store position: ((k>>2)&7)<<2 == (t&7)<<2 (constant per thread).
    const int st_r_base = t >> 3;
    const int st_kc     = (t & 7) * 4;
    const int st_xor    = (t & 7) << 2;

    float bestv[8];
    int   besti[8];
    #pragma unroll
    for (int i = 0; i < 8; ++i) { bestv[i] = 3.4e38f; besti[i] = 0; }

    for (int ct = 0; ct < 8; ++ct) {           // 1024 clusters / BN
        const int col0 = ct * BN;
        float acc[8][8];
        #pragma unroll
        for (int i = 0; i < 8; ++i)
            #pragma unroll
            for (int j = 0; j < 8; ++j) acc[i][j] = 0.0f;

        for (int k0 = 0; k0 < D_DIM; k0 += BK) {
            __syncthreads();                   // previous tile reads done
            // stage A (feat rows) transposed+swizzled
            #pragma unroll
            for (int i = 0; i < 4; ++i) {
                const int r  = i * 32 + st_r_base;
                const float4 v = *(const float4*)(feat + (size_t)(row0 + r) * D_DIM + k0 + st_kc);
                const int rs = r ^ st_xor;
                As[st_kc + 0][rs] = v.x;
                As[st_kc + 1][rs] = v.y;
                As[st_kc + 2][rs] = v.z;
                As[st_kc + 3][rs] = v.w;
            }
            // stage B (cluster rows) transposed+swizzled
            #pragma unroll
            for (int i = 0; i < 4; ++i) {
                const int r  = i * 32 + st_r_base;
                const float4 v = *(const float4*)(clusters + (size_t)(col0 + r) * D_DIM + k0 + st_kc);
                const int rs = r ^ st_xor;
                Bs[st_kc + 0][rs] = v.x;
                Bs[st_kc + 1][rs] = v.y;
                Bs[st_kc + 2][rs] = v.z;
                Bs[st_kc + 3][rs] = v.w;
            }
            __syncthreads();

            #pragma unroll
            for (int kk = 0; kk < BK; ++kk) {
                const int xr = ((kk >> 2) & 7) << 2;   // constant-folds (unrolled)
                const float4 a0 = *(const float4*)&As[kk][(ty * 8)     ^ xr];
                const float4 a1 = *(const float4*)&As[kk][(ty * 8 + 4) ^ xr];
                const float4 b0 = *(const float4*)&Bs[kk][(tx * 8)     ^ xr];
                const float4 b1 = *(const float4*)&Bs[kk][(tx * 8 + 4) ^ xr];
                float a[8] = {a0.x, a0.y, a0.z, a0.w, a1.x, a1.y, a1.z, a1.w};
                float b[8] = {b0.x, b0.y, b0.z, b0.w, b1.x, b1.y, b1.z, b1.w};
                #pragma unroll
                for (int i = 0; i < 8; ++i)
                    #pragma unroll
                    for (int j = 0; j < 8; ++j)
                        acc[i][j] = fmaf(a[i], b[j], acc[i][j]);
            }
        }

        // fold this col-tile into running argmin (cols ascending -> first-min tie-break)
        #pragma unroll
        for (int j = 0; j < 8; ++j) {
            const int col = col0 + tx * 8 + j;
            const float cc = c2[col];
            #pragma unroll
            for (int i = 0; i < 8; ++i) {
                const float score = fmaf(-2.0f, acc[i][j], cc);
                if (score < bestv[i]) { bestv[i] = score; besti[i] = col; }
            }
        }
    }

    // cross-thread reduce: 16 tx-partials per row, reuse LDS
    __syncthreads();
    float (*rv)[16] = (float(*)[16])As;   // [128][16] floats, fits in As
    int   (*ri)[16] = (int(*)[16])Bs;
    #pragma unroll
    for (int i = 0; i < 8; ++i) {
        rv[ty * 8 + i][tx] = bestv[i];
        ri[ty * 8 + i][tx] = besti[i];
    }
    __syncthreads();
    if (t < BM) {
        float bv = rv[t][0];
        int   bi = ri[t][0];
        #pragma unroll
        for (int x = 1; x < 16; ++x) {
            const float v  = rv[t][x];
            const int   ix = ri[t][x];
            if (v < bv || (v == bv && ix < bi)) { bv = v; bi = ix; }
        }
        out[row0 + t] = bi;
    }
}

extern "C" void kernel_launch(void* const* d_in, const int* in_sizes, int n_in,
                              void* d_out, int out_size, void* d_ws, size_t ws_size,
                              hipStream_t stream) {
    const float* feat     = (const float*)d_in[0];
    const float* clusters = (const float*)d_in[1];
    int*   out = (int*)d_out;
    float* c2  = (float*)d_ws;                 // 1024 floats of scratch

    const int M = in_sizes[0] / D_DIM;         // 65536
    const int C = in_sizes[1] / D_DIM;         // 1024

    c2_kernel<<<C / 4, 256, 0, stream>>>(clusters, c2);
    argmin_kernel<<<M / BM, 256, 0, stream>>>(feat, clusters, c2, out);
}